// Round 1
// baseline (111.182 us; speedup 1.0000x reference)
//
#include <hip/hip_runtime.h>

// Problem constants (fixed by the reference)
#define BB 4
#define NN 50000
#define GG 2
#define EE 500000
#define HH 64
#define RR 16

// ---------------------------------------------------------------------------
// Kernel A: prep
//  - pmT[n] = {pert_mask[0,n], ..., pert_mask[3,n]}  (transposed, float4)
//  - pw[h] = sum_k lin_w[k]*post_w[k,h]; pb[h] = sum_k lin_b[k]*post_w[k,h]
//  - wts[b,g] = softmax_g(ctx_emb[b] @ mix_w + mix_b)
// ---------------------------------------------------------------------------
__global__ __launch_bounds__(256) void prep_kernel(
    const float* __restrict__ pert_mask, const float* __restrict__ ctx,
    const float* __restrict__ lin_w, const float* __restrict__ lin_b,
    const float* __restrict__ post_w, const float* __restrict__ mix_w,
    const float* __restrict__ mix_b,
    float4* __restrict__ pmT, float* __restrict__ pw, float* __restrict__ pb,
    float* __restrict__ wts)
{
    int n = blockIdx.x * 256 + threadIdx.x;
    if (n < NN) {
        pmT[n] = make_float4(pert_mask[0*NN + n], pert_mask[1*NN + n],
                             pert_mask[2*NN + n], pert_mask[3*NN + n]);
    }
    if (blockIdx.x == 0) {
        int t = threadIdx.x;
        if (t < HH) {
            float a = 0.f, c = 0.f;
            for (int k = 0; k < HH; ++k) {
                float w = post_w[k*HH + t];
                a = fmaf(lin_w[k], w, a);
                c = fmaf(lin_b[k], w, c);
            }
            pw[t] = a; pb[t] = c;
        } else if (t < HH + BB) {
            int b = t - HH;
            float l0 = mix_b[0], l1 = mix_b[1];
            for (int h = 0; h < HH; ++h) {
                float cv = ctx[b*HH + h];
                l0 = fmaf(cv, mix_w[h*GG + 0], l0);
                l1 = fmaf(cv, mix_w[h*GG + 1], l1);
            }
            float m = fmaxf(l0, l1);
            float e0 = __expf(l0 - m), e1 = __expf(l1 - m);
            float inv = 1.f / (e0 + e1);
            wts[b*GG + 0] = e0 * inv;
            wts[b*GG + 1] = e1 * inv;
        }
    }
}

// ---------------------------------------------------------------------------
// Kernel B: per-edge gate + scalar scatter
//  w[e] = edge_weight[e] * sigmoid(<gate_u[g,src], gate_v[g,dst]>)
//  s0[g,dst]   += w
//  s1[g,b,dst] += w * pert_mask[b,src]   (skipped exactly when mask==0)
// ---------------------------------------------------------------------------
__global__ __launch_bounds__(256) void edge_kernel(
    const int* __restrict__ esrc, const int* __restrict__ edst,
    const float* __restrict__ ewgt, const float* __restrict__ gu,
    const float* __restrict__ gv, const float4* __restrict__ pmT,
    float* __restrict__ s0, float* __restrict__ s1)
{
    int e = blockIdx.x * 256 + threadIdx.x;
    int g = blockIdx.y;
    if (e >= EE) return;
    size_t ge = (size_t)g * EE + e;
    int s = esrc[ge], d = edst[ge];
    const float4* u = (const float4*)(gu + ((size_t)g * NN + s) * RR);
    const float4* v = (const float4*)(gv + ((size_t)g * NN + d) * RR);
    float dot = 0.f;
#pragma unroll
    for (int i = 0; i < 4; ++i) {
        float4 a = u[i], b = v[i];
        dot = fmaf(a.x, b.x, dot);
        dot = fmaf(a.y, b.y, dot);
        dot = fmaf(a.z, b.z, dot);
        dot = fmaf(a.w, b.w, dot);
    }
    float w = ewgt[ge] / (1.f + __expf(-dot));  // weight * sigmoid(dot)
    atomicAdd(&s0[g * NN + d], w);
    float4 pm = pmT[s];
    float* s1g = s1 + (size_t)g * BB * NN + d;
    if (pm.x != 0.f) atomicAdd(s1g + 0 * NN, w * pm.x);
    if (pm.y != 0.f) atomicAdd(s1g + 1 * NN, w * pm.y);
    if (pm.z != 0.f) atomicAdd(s1g + 2 * NN, w * pm.z);
    if (pm.w != 0.f) atomicAdd(s1g + 3 * NN, w * pm.w);
}

// ---------------------------------------------------------------------------
// Kernel C: per-node ReLU + mean, mix weights folded in.
//  thread t owns (b = t>>6, h = t&63); block processes CH nodes staged in LDS.
//  out[b,h] += wts[b,g]/N * sum_n relu(s1[g,b,n]*pw[h] + s0[g,n]*pb[h] + post_b[h])
// ---------------------------------------------------------------------------
#define CH 256

__global__ __launch_bounds__(256) void node_kernel(
    const float* __restrict__ s0, const float* __restrict__ s1,
    const float* __restrict__ pw, const float* __restrict__ pb,
    const float* __restrict__ post_b, const float* __restrict__ wts,
    float* __restrict__ out)
{
    int g = blockIdx.y;
    int n0 = blockIdx.x * CH;
    int cnt = min(CH, NN - n0);
    __shared__ float ls0[CH];
    __shared__ float ls1[BB][CH];
    int t = threadIdx.x;
    for (int i = t; i < cnt; i += 256) ls0[i] = s0[g * NN + n0 + i];
#pragma unroll
    for (int b = 0; b < BB; ++b)
        for (int i = t; i < cnt; i += 256)
            ls1[b][i] = s1[((size_t)g * BB + b) * NN + n0 + i];
    __syncthreads();
    int b = t >> 6, h = t & 63;
    float pwh = pw[h], pbh = pb[h], bias = post_b[h];
    float acc = 0.f;
    for (int i = 0; i < cnt; ++i) {
        float x = fmaf(ls1[b][i], pwh, fmaf(ls0[i], pbh, bias));
        acc += fmaxf(x, 0.f);
    }
    float scale = wts[b * GG + g] * (1.0f / NN);
    atomicAdd(&out[b * HH + h], acc * scale);
}

// ---------------------------------------------------------------------------
extern "C" void kernel_launch(void* const* d_in, const int* in_sizes, int n_in,
                              void* d_out, int out_size, void* d_ws, size_t ws_size,
                              hipStream_t stream) {
    const float* pert_mask = (const float*)d_in[0];
    const float* ctx       = (const float*)d_in[1];
    const int*   esrc      = (const int*)d_in[2];
    const int*   edst      = (const int*)d_in[3];
    const float* ewgt      = (const float*)d_in[4];
    const float* gu        = (const float*)d_in[5];
    const float* gv        = (const float*)d_in[6];
    const float* lin_w     = (const float*)d_in[7];
    const float* lin_b     = (const float*)d_in[8];
    const float* post_w    = (const float*)d_in[9];
    const float* post_b    = (const float*)d_in[10];
    const float* mix_w     = (const float*)d_in[11];
    const float* mix_b     = (const float*)d_in[12];
    float* out = (float*)d_out;

    float* ws  = (float*)d_ws;
    float4* pmT = (float4*)ws;               // N float4          = 200000 f
    float* s0   = ws + (size_t)NN * 4;       // G*N               = 100000 f
    float* s1   = s0 + (size_t)GG * NN;      // G*B*N             = 400000 f
    float* pw   = s1 + (size_t)GG * BB * NN; // H
    float* pb   = pw + HH;                   // H
    float* wts  = pb + HH;                   // B*G

    // zero the accumulators (s0 and s1 are contiguous) and the output
    hipMemsetAsync(s0, 0, (size_t)(GG * NN + GG * BB * NN) * sizeof(float), stream);
    hipMemsetAsync(d_out, 0, (size_t)BB * HH * sizeof(float), stream);

    prep_kernel<<<(NN + 255) / 256, 256, 0, stream>>>(
        pert_mask, ctx, lin_w, lin_b, post_w, mix_w, mix_b, pmT, pw, pb, wts);

    dim3 eg((EE + 255) / 256, GG);
    edge_kernel<<<eg, 256, 0, stream>>>(esrc, edst, ewgt, gu, gv, pmT, s0, s1);

    dim3 ng((NN + CH - 1) / CH, GG);
    node_kernel<<<ng, 256, 0, stream>>>(s0, s1, pw, pb, post_b, wts, out);
}